// Round 1
// baseline (497.778 us; speedup 1.0000x reference)
//
#include <hip/hip_runtime.h>
#include <cstdint>
#include <cstddef>

// Transformer block, B=2 S=2048 D=1024 H=16 DH=64 DFF=4096.
// Round 1: correctness-first bf16 MFMA pipeline.
//   LN1 -> QKV GEMMs -> flash attention -> Wo GEMM (+residual) -> LN2
//   -> FF1 GEMM (+GELU) -> FF2 GEMM (+residual) -> d_out (fp32)

#define DEV static __device__ __forceinline__

typedef unsigned short u16;
typedef __bf16 bf16x8 __attribute__((ext_vector_type(8)));
typedef u16    u16x8  __attribute__((ext_vector_type(8)));
typedef u16    u16x4  __attribute__((ext_vector_type(4)));
typedef float  f32x4  __attribute__((ext_vector_type(4)));

DEV u16 f2bf(float f) {
  unsigned u = __builtin_bit_cast(unsigned, f);
  u += 0x7fffu + ((u >> 16) & 1u);   // RNE; inputs are finite
  return (u16)(u >> 16);
}

// ---------------------------------------------------------------------------
// Weight transpose + fp32->bf16 convert:  in[R][C] fp32 -> out[C][R] bf16
// ---------------------------------------------------------------------------
__global__ __launch_bounds__(256)
void tconv(const float* __restrict__ in, u16* __restrict__ out, int R, int C)
{
  __shared__ float tile[32][33];
  const int tx = threadIdx.x & 31, ty = threadIdx.x >> 5;   // 32 x 8
  const int r0 = blockIdx.y * 32, c0 = blockIdx.x * 32;
#pragma unroll
  for (int i = 0; i < 4; ++i)
    tile[ty + 8*i][tx] = in[(size_t)(r0 + ty + 8*i) * C + c0 + tx];
  __syncthreads();
#pragma unroll
  for (int i = 0; i < 4; ++i)
    out[(size_t)(c0 + ty + 8*i) * R + r0 + tx] = f2bf(tile[tx][ty + 8*i]);
}

// ---------------------------------------------------------------------------
// LayerNorm over D=1024, one block (256 threads) per row, out bf16
// ---------------------------------------------------------------------------
__global__ __launch_bounds__(256)
void ln_fwd(const float* __restrict__ x, const float* __restrict__ g,
            const float* __restrict__ b, u16* __restrict__ out)
{
  const int row = blockIdx.x, t = threadIdx.x;
  const float4 v = ((const float4*)(x + (size_t)row * 1024))[t];
  float s1 = v.x + v.y + v.z + v.w;
  float s2 = v.x*v.x + v.y*v.y + v.z*v.z + v.w*v.w;
#pragma unroll
  for (int d = 1; d < 64; d <<= 1) {
    s1 += __shfl_xor(s1, d, 64);
    s2 += __shfl_xor(s2, d, 64);
  }
  __shared__ float sh[8];
  const int w = t >> 6;
  if ((t & 63) == 0) { sh[w] = s1; sh[w + 4] = s2; }
  __syncthreads();
  s1 = sh[0] + sh[1] + sh[2] + sh[3];
  s2 = sh[4] + sh[5] + sh[6] + sh[7];
  const float mu  = s1 * (1.0f / 1024.0f);
  const float var = s2 * (1.0f / 1024.0f) - mu * mu;
  const float rs  = rsqrtf(var + 1e-5f);
  const float4 gv = ((const float4*)g)[t];
  const float4 bv = ((const float4*)b)[t];
  u16x4 o;
  o[0] = f2bf((v.x - mu) * rs * gv.x + bv.x);
  o[1] = f2bf((v.y - mu) * rs * gv.y + bv.y);
  o[2] = f2bf((v.z - mu) * rs * gv.z + bv.z);
  o[3] = f2bf((v.w - mu) * rs * gv.w + bv.w);
  *(u16x4*)(out + (size_t)row * 1024 + t * 4) = o;
}

// ---------------------------------------------------------------------------
// GEMM: C[M,N] = A[M,K](bf16) @ Bt[N,K]^T(bf16) + bias, fused epilogues.
// 128x128 tile, 4 waves (2x2), 16x16x32 bf16 MFMA, BK=32, reg-staged LDS.
// ---------------------------------------------------------------------------
#define EPI_QKV  0   // out bf16 [B,H,S,DH]
#define EPI_RES  1   // out fp32 = acc + bias + res
#define EPI_GELU 2   // out bf16 = gelu(acc + bias)

template<int EPI>
__global__ __launch_bounds__(256)
void gemm_bt(const u16* __restrict__ A, const u16* __restrict__ Bt,
             const float* __restrict__ bias, const float* __restrict__ res,
             float* __restrict__ outf, u16* __restrict__ outb,
             int N, int K)
{
  __shared__ u16 As[128 * 32];
  __shared__ u16 Bs[128 * 32];
  const int t = threadIdx.x;
  const int lane = t & 63;
  const int w = t >> 6;
  const int wr = w >> 1, wc = w & 1;
  const int m0 = blockIdx.y * 128, n0 = blockIdx.x * 128;
  const int li = lane & 15, lg = lane >> 4;

  const int idx0 = t * 8;           // element idx in 128x32 tile
  const int idx1 = idx0 + 2048;
  const u16* Ag0 = A  + (size_t)(m0 + (idx0 >> 5)) * K + (idx0 & 31);
  const u16* Ag1 = A  + (size_t)(m0 + (idx1 >> 5)) * K + (idx1 & 31);
  const u16* Bg0 = Bt + (size_t)(n0 + (idx0 >> 5)) * K + (idx0 & 31);
  const u16* Bg1 = Bt + (size_t)(n0 + (idx1 >> 5)) * K + (idx1 & 31);

  f32x4 acc[4][4] = {};

  for (int k0 = 0; k0 < K; k0 += 32) {
    u16x8 va0 = *(const u16x8*)(Ag0 + k0);
    u16x8 va1 = *(const u16x8*)(Ag1 + k0);
    u16x8 vb0 = *(const u16x8*)(Bg0 + k0);
    u16x8 vb1 = *(const u16x8*)(Bg1 + k0);
    __syncthreads();                 // prev iter's LDS reads done
    *(u16x8*)&As[idx0] = va0;
    *(u16x8*)&As[idx1] = va1;
    *(u16x8*)&Bs[idx0] = vb0;
    *(u16x8*)&Bs[idx1] = vb1;
    __syncthreads();                 // staging visible
    bf16x8 af[4], bf[4];
#pragma unroll
    for (int i = 0; i < 4; ++i)
      af[i] = *(const bf16x8*)&As[(wr*64 + i*16 + li)*32 + lg*8];
#pragma unroll
    for (int i = 0; i < 4; ++i)
      bf[i] = *(const bf16x8*)&Bs[(wc*64 + i*16 + li)*32 + lg*8];
#pragma unroll
    for (int mi = 0; mi < 4; ++mi)
#pragma unroll
      for (int ni = 0; ni < 4; ++ni)
        acc[mi][ni] = __builtin_amdgcn_mfma_f32_16x16x32_bf16(
            af[mi], bf[ni], acc[mi][ni], 0, 0, 0);
  }

  // C layout: col = lane&15, row = (lane>>4)*4 + reg   [verified m89/m91]
  const int crow = wr * 64 + lg * 4;
  const int ccol = wc * 64 + li;
#pragma unroll
  for (int mi = 0; mi < 4; ++mi) {
#pragma unroll
    for (int ni = 0; ni < 4; ++ni) {
#pragma unroll
      for (int r = 0; r < 4; ++r) {
        const int gm = m0 + crow + mi * 16 + r;
        const int gn = n0 + ccol + ni * 16;
        float v = acc[mi][ni][r] + bias[gn];
        if (EPI == EPI_QKV) {
          // [B,S,D] row gm, col gn -> [B,H,S,DH]
          const int b_ = gm >> 11, s_ = gm & 2047;
          const int h_ = gn >> 6,  d_ = gn & 63;
          outb[((size_t)(b_ * 16 + h_) * 2048 + s_) * 64 + d_] = f2bf(v);
        } else if (EPI == EPI_RES) {
          const size_t o = (size_t)gm * N + gn;
          outf[o] = v + res[o];
        } else {
          const float gl = 0.5f * v * (1.0f + erff(v * 0.70710678f));
          outb[(size_t)gm * N + gn] = f2bf(gl);
        }
      }
    }
  }
}

// ---------------------------------------------------------------------------
// Causal flash attention. q,k,v bf16 [B*H, S, 64]. Out bf16 [B,S,D].
// Block: 256 thr / 4 waves; 64 q-rows per block (16 per wave); kv tiles of 64.
// ---------------------------------------------------------------------------
__global__ __launch_bounds__(256)
void attn_fwd(const u16* __restrict__ qb, const u16* __restrict__ kb,
              const u16* __restrict__ vb, u16* __restrict__ ob)
{
  __shared__ u16 Ks[64 * 64];        // [kv][dh]
  __shared__ u16 Vt[64 * 64];        // [dh][kv]
  __shared__ u16 Ps[4][16 * 64];     // per-wave P tile [q][kv]
  const int t = threadIdx.x, w = t >> 6, lane = t & 63;
  const int li = lane & 15, lg = lane >> 4;
  const int bh = blockIdx.y;
  const int q0 = blockIdx.x * 64;

  // Q fragments (A-operand): row = q0 + w*16 + li, k = lg*8.. (+32)
  const size_t qrow = (size_t)bh * 2048 + q0 + w * 16 + li;
  const bf16x8 aq0 = *(const bf16x8*)(qb + qrow * 64 + lg * 8);
  const bf16x8 aq1 = *(const bf16x8*)(qb + qrow * 64 + lg * 8 + 32);

  f32x4 o[4] = {};
  float mrun[4], lrun[4];
#pragma unroll
  for (int r = 0; r < 4; ++r) { mrun[r] = -1e30f; lrun[r] = 0.0f; }

  const u16* kbase = kb + (size_t)bh * 2048 * 64;
  const u16* vbase = vb + (size_t)bh * 2048 * 64;
  const int ntile = blockIdx.x + 1;

  for (int tk = 0; tk < ntile; ++tk) {
    const int kv0 = tk * 64;
    const u16x8 k0v = *(const u16x8*)(kbase + (size_t)kv0 * 64 + t * 8);
    const u16x8 k1v = *(const u16x8*)(kbase + (size_t)kv0 * 64 + t * 8 + 2048);
    const u16x8 v0v = *(const u16x8*)(vbase + (size_t)kv0 * 64 + t * 8);
    const u16x8 v1v = *(const u16x8*)(vbase + (size_t)kv0 * 64 + t * 8 + 2048);
    __syncthreads();                       // prev iter's LDS reads done
    *(u16x8*)&Ks[t * 8]        = k0v;
    *(u16x8*)&Ks[t * 8 + 2048] = k1v;
    {
      const int ia = t * 8, kva = ia >> 6, da = ia & 63;
#pragma unroll
      for (int j = 0; j < 8; ++j) Vt[(da + j) * 64 + kva] = v0v[j];
      const int ib = ia + 2048, kvb = ib >> 6, db = ib & 63;
#pragma unroll
      for (int j = 0; j < 8; ++j) Vt[(db + j) * 64 + kvb] = v1v[j];
    }
    __syncthreads();                       // staging visible

    // S = Q K^T * 0.125  (16 q x 64 kv per wave)
    f32x4 s[4];
#pragma unroll
    for (int cf = 0; cf < 4; ++cf) {
      const bf16x8 bk0 = *(const bf16x8*)&Ks[(cf * 16 + li) * 64 + lg * 8];
      const bf16x8 bk1 = *(const bf16x8*)&Ks[(cf * 16 + li) * 64 + lg * 8 + 32];
      f32x4 z = {};
      z = __builtin_amdgcn_mfma_f32_16x16x32_bf16(aq0, bk0, z, 0, 0, 0);
      z = __builtin_amdgcn_mfma_f32_16x16x32_bf16(aq1, bk1, z, 0, 0, 0);
      s[cf] = z;
    }
    const int row0 = q0 + w * 16 + lg * 4;
    const bool last = (tk == ntile - 1);
#pragma unroll
    for (int cf = 0; cf < 4; ++cf)
#pragma unroll
      for (int r = 0; r < 4; ++r) {
        float sv = s[cf][r] * 0.125f;
        if (last && (kv0 + cf * 16 + li > row0 + r)) sv = -1e30f;
        s[cf][r] = sv;
      }

    // online softmax over this tile (row stats live in 16-lane groups)
    float pmax[4];
#pragma unroll
    for (int r = 0; r < 4; ++r)
      pmax[r] = fmaxf(fmaxf(s[0][r], s[1][r]), fmaxf(s[2][r], s[3][r]));
#pragma unroll
    for (int d = 1; d < 16; d <<= 1)
#pragma unroll
      for (int r = 0; r < 4; ++r)
        pmax[r] = fmaxf(pmax[r], __shfl_xor(pmax[r], d, 64));
    float mnew[4], scl[4];
#pragma unroll
    for (int r = 0; r < 4; ++r) {
      mnew[r] = fmaxf(mrun[r], pmax[r]);
      scl[r]  = __expf(mrun[r] - mnew[r]);
    }
    float p[4][4], ps[4] = {0.f, 0.f, 0.f, 0.f};
#pragma unroll
    for (int cf = 0; cf < 4; ++cf)
#pragma unroll
      for (int r = 0; r < 4; ++r) {
        p[cf][r] = __expf(s[cf][r] - mnew[r]);
        ps[r] += p[cf][r];
      }
#pragma unroll
    for (int d = 1; d < 16; d <<= 1)
#pragma unroll
      for (int r = 0; r < 4; ++r)
        ps[r] += __shfl_xor(ps[r], d, 64);
#pragma unroll
    for (int r = 0; r < 4; ++r) {
      lrun[r] = lrun[r] * scl[r] + ps[r];
      mrun[r] = mnew[r];
    }
#pragma unroll
    for (int n = 0; n < 4; ++n)
#pragma unroll
      for (int r = 0; r < 4; ++r) o[n][r] *= scl[r];

    // P (C-layout) -> LDS -> A-fragments
#pragma unroll
    for (int cf = 0; cf < 4; ++cf)
#pragma unroll
      for (int r = 0; r < 4; ++r)
        Ps[w][(lg * 4 + r) * 64 + cf * 16 + li] = f2bf(p[cf][r]);
    __syncthreads();                       // order P writes before reads

#pragma unroll
    for (int ks = 0; ks < 2; ++ks) {
      const bf16x8 ap = *(const bf16x8*)&Ps[w][li * 64 + lg * 8 + ks * 32];
#pragma unroll
      for (int n = 0; n < 4; ++n) {
        const bf16x8 bv = *(const bf16x8*)&Vt[(n * 16 + li) * 64 + lg * 8 + ks * 32];
        o[n] = __builtin_amdgcn_mfma_f32_16x16x32_bf16(ap, bv, o[n], 0, 0, 0);
      }
    }
  }

  float inv[4];
#pragma unroll
  for (int r = 0; r < 4; ++r) inv[r] = 1.0f / lrun[r];
  const int b_ = bh >> 4, h_ = bh & 15;
#pragma unroll
  for (int n = 0; n < 4; ++n)
#pragma unroll
    for (int r = 0; r < 4; ++r) {
      const int rowg = q0 + w * 16 + lg * 4 + r;
      ob[((size_t)b_ * 2048 + rowg) * 1024 + h_ * 64 + n * 16 + li] =
          f2bf(o[n][r] * inv[r]);
    }
}

// ---------------------------------------------------------------------------
extern "C" void kernel_launch(void* const* d_in, const int* in_sizes, int n_in,
                              void* d_out, int out_size, void* d_ws, size_t ws_size,
                              hipStream_t stream) {
  const float* x    = (const float*)d_in[0];
  const float* ln1g = (const float*)d_in[1];
  const float* ln1b = (const float*)d_in[2];
  const float* Wq   = (const float*)d_in[3];
  const float* bq   = (const float*)d_in[4];
  const float* Wk   = (const float*)d_in[5];
  const float* bk   = (const float*)d_in[6];
  const float* Wv   = (const float*)d_in[7];
  const float* bv   = (const float*)d_in[8];
  const float* Wo   = (const float*)d_in[9];
  const float* bo   = (const float*)d_in[10];
  const float* ln2g = (const float*)d_in[11];
  const float* ln2b = (const float*)d_in[12];
  const float* W1   = (const float*)d_in[13];
  const float* b1   = (const float*)d_in[14];
  const float* W2   = (const float*)d_in[15];
  const float* b2   = (const float*)d_in[16];

  char* ws = (char*)d_ws;
  const size_t MB = 1u << 20;           // total ws use: 80 MB
  u16*   hb   = (u16*)(ws + 0);         //  8 MB  LN1 out bf16 [4096,1024]
  u16*   Wqt  = (u16*)(ws + 8  * MB);   //  2 MB  each, bf16 [N][K]
  u16*   Wkt  = (u16*)(ws + 10 * MB);
  u16*   Wvt  = (u16*)(ws + 12 * MB);
  u16*   Wot  = (u16*)(ws + 14 * MB);
  u16*   W1t  = (u16*)(ws + 16 * MB);   //  8 MB  [4096][1024]
  u16*   W2t  = (u16*)(ws + 24 * MB);   //  8 MB  [1024][4096]
  u16*   qbuf = (u16*)(ws + 32 * MB);   //  8 MB  [B,H,S,DH]
  u16*   kbuf = (u16*)(ws + 40 * MB);
  u16*   vbuf = (u16*)(ws + 48 * MB);
  u16*   aob  = (u16*)(ws + 56 * MB);   //  8 MB  attn out [B,S,D]
  float* x2   = (float*)(ws + 64 * MB); // 16 MB  fp32 residual
  u16*   h2   = hb;                     // reuse (hb dead after QKV)
  u16*   ff1  = qbuf;                   // reuse 32 MB (q/k/v/ao dead after Wo)

  const dim3 blk(256);
  tconv<<<dim3(32, 32),  blk, 0, stream>>>(Wq, Wqt, 1024, 1024);
  tconv<<<dim3(32, 32),  blk, 0, stream>>>(Wk, Wkt, 1024, 1024);
  tconv<<<dim3(32, 32),  blk, 0, stream>>>(Wv, Wvt, 1024, 1024);
  tconv<<<dim3(32, 32),  blk, 0, stream>>>(Wo, Wot, 1024, 1024);
  tconv<<<dim3(128, 32), blk, 0, stream>>>(W1, W1t, 1024, 4096);
  tconv<<<dim3(32, 128), blk, 0, stream>>>(W2, W2t, 4096, 1024);

  ln_fwd<<<4096, blk, 0, stream>>>(x, ln1g, ln1b, hb);

  gemm_bt<EPI_QKV><<<dim3(8, 32), blk, 0, stream>>>(hb, Wqt, bq, nullptr, nullptr, qbuf, 1024, 1024);
  gemm_bt<EPI_QKV><<<dim3(8, 32), blk, 0, stream>>>(hb, Wkt, bk, nullptr, nullptr, kbuf, 1024, 1024);
  gemm_bt<EPI_QKV><<<dim3(8, 32), blk, 0, stream>>>(hb, Wvt, bv, nullptr, nullptr, vbuf, 1024, 1024);

  attn_fwd<<<dim3(32, 32), blk, 0, stream>>>(qbuf, kbuf, vbuf, aob);

  gemm_bt<EPI_RES><<<dim3(8, 32), blk, 0, stream>>>(aob, Wot, bo, x, x2, nullptr, 1024, 1024);

  ln_fwd<<<4096, blk, 0, stream>>>(x2, ln2g, ln2b, h2);

  gemm_bt<EPI_GELU><<<dim3(32, 32), blk, 0, stream>>>(h2, W1t, b1, nullptr, nullptr, ff1, 4096, 1024);
  gemm_bt<EPI_RES><<<dim3(8, 32), blk, 0, stream>>>(ff1, W2t, b2, x2, (float*)d_out, nullptr, 1024, 4096);
}

// Round 2
// 360.895 us; speedup vs baseline: 1.3793x; 1.3793x over previous
//
#include <hip/hip_runtime.h>
#include <cstdint>
#include <cstddef>

// Transformer block, B=2 S=2048 D=1024 H=16 DH=64 DFF=4096.
// Round 2: global_load_lds GEMMs (m97 structure), fused QKV (N=3072),
// swizzled-LDS flash attention with KVBLK=128 and pre-transposed V.

#define DEV static __device__ __forceinline__

typedef unsigned short u16;
typedef __bf16 bf16x8 __attribute__((ext_vector_type(8)));
typedef u16    u16x8  __attribute__((ext_vector_type(8)));
typedef u16    u16x4  __attribute__((ext_vector_type(4)));
typedef float  f32x4  __attribute__((ext_vector_type(4)));

DEV u16 f2bf(float f) {
  unsigned u = __builtin_bit_cast(unsigned, f);
  u += 0x7fffu + ((u >> 16) & 1u);   // RNE; inputs are finite
  return (u16)(u >> 16);
}

// async global->LDS, 16B per lane. LDS dest must be linear in lane order.
DEV void gl16(const void* g, void* l) {
  __builtin_amdgcn_global_load_lds(
      (const __attribute__((address_space(1))) unsigned*)g,
      (__attribute__((address_space(3))) unsigned*)l, 16, 0, 0);
}

// ---------------------------------------------------------------------------
// Weight transpose + fp32->bf16 convert:  in[R][C] fp32 -> out[C][R] bf16
// ---------------------------------------------------------------------------
__global__ __launch_bounds__(256)
void tconv(const float* __restrict__ in, u16* __restrict__ out, int R, int C)
{
  __shared__ float tile[32][33];
  const int tx = threadIdx.x & 31, ty = threadIdx.x >> 5;   // 32 x 8
  const int r0 = blockIdx.y * 32, c0 = blockIdx.x * 32;
#pragma unroll
  for (int i = 0; i < 4; ++i)
    tile[ty + 8*i][tx] = in[(size_t)(r0 + ty + 8*i) * C + c0 + tx];
  __syncthreads();
#pragma unroll
  for (int i = 0; i < 4; ++i)
    out[(size_t)(c0 + ty + 8*i) * R + r0 + tx] = f2bf(tile[tx][ty + 8*i]);
}

// ---------------------------------------------------------------------------
// V transpose bf16: in [BH][2048][64] -> out [BH][64][2048]
// ---------------------------------------------------------------------------
__global__ __launch_bounds__(256)
void vtrans(const u16* __restrict__ in, u16* __restrict__ out)
{
  __shared__ u16 tile[32][33];
  const int tx = threadIdx.x & 31, ty = threadIdx.x >> 5;
  const int s0 = blockIdx.x * 32, d0 = blockIdx.y * 32;
  const size_t base = (size_t)blockIdx.z * 2048 * 64;
#pragma unroll
  for (int i = 0; i < 4; ++i)
    tile[ty + 8*i][tx] = in[base + (size_t)(s0 + ty + 8*i) * 64 + d0 + tx];
  __syncthreads();
#pragma unroll
  for (int i = 0; i < 4; ++i)
    out[base + (size_t)(d0 + ty + 8*i) * 2048 + s0 + tx] = tile[tx][ty + 8*i];
}

// ---------------------------------------------------------------------------
// LayerNorm over D=1024, one block (256 threads) per row, out bf16
// ---------------------------------------------------------------------------
__global__ __launch_bounds__(256)
void ln_fwd(const float* __restrict__ x, const float* __restrict__ g,
            const float* __restrict__ b, u16* __restrict__ out)
{
  const int row = blockIdx.x, t = threadIdx.x;
  const float4 v = ((const float4*)(x + (size_t)row * 1024))[t];
  float s1 = v.x + v.y + v.z + v.w;
  float s2 = v.x*v.x + v.y*v.y + v.z*v.z + v.w*v.w;
#pragma unroll
  for (int d = 1; d < 64; d <<= 1) {
    s1 += __shfl_xor(s1, d, 64);
    s2 += __shfl_xor(s2, d, 64);
  }
  __shared__ float sh[8];
  const int w = t >> 6;
  if ((t & 63) == 0) { sh[w] = s1; sh[w + 4] = s2; }
  __syncthreads();
  s1 = sh[0] + sh[1] + sh[2] + sh[3];
  s2 = sh[4] + sh[5] + sh[6] + sh[7];
  const float mu  = s1 * (1.0f / 1024.0f);
  const float var = s2 * (1.0f / 1024.0f) - mu * mu;
  const float rs  = rsqrtf(var + 1e-5f);
  const float4 gv = ((const float4*)g)[t];
  const float4 bv = ((const float4*)b)[t];
  u16x4 o;
  o[0] = f2bf((v.x - mu) * rs * gv.x + bv.x);
  o[1] = f2bf((v.y - mu) * rs * gv.y + bv.y);
  o[2] = f2bf((v.z - mu) * rs * gv.z + bv.z);
  o[3] = f2bf((v.w - mu) * rs * gv.w + bv.w);
  *(u16x4*)(out + (size_t)row * 1024 + t * 4) = o;
}

// ---------------------------------------------------------------------------
// GEMM: C[M,N] = A[M,K](bf16) @ Bt[N,K]^T(bf16) + bias, fused epilogues.
// BMx128 tile, 4 waves (2x2), 16x16x32 bf16 MFMA, BK=32, global_load_lds.
// ---------------------------------------------------------------------------
#define EPI_QKV  0   // out bf16 [B,H,S,DH] x3 (fused QKV, N=3072)
#define EPI_RES  1   // out fp32 = acc + bias + res
#define EPI_GELU 2   // out bf16 = gelu(acc + bias)

template<int EPI, int BM>
__global__ __launch_bounds__(256)
void gemm_bt(const u16* __restrict__ A, const u16* __restrict__ Bt,
             const float* __restrict__ b0, const float* __restrict__ b1,
             const float* __restrict__ b2, const float* __restrict__ res,
             float* __restrict__ outf, u16* __restrict__ o0,
             u16* __restrict__ o1, u16* __restrict__ o2,
             int N, int K)
{
  constexpr int MI = BM / 32;          // 16-row A-frags per wave
  constexpr int LA = (BM * 32) / 2048; // gl16 rounds for A (1 or 2)
  __shared__ u16 As[BM * 32];
  __shared__ u16 Bs[128 * 32];
  const int t = threadIdx.x, lane = t & 63, w = t >> 6;
  const int wr = w >> 1, wc = w & 1;
  const int m0 = blockIdx.y * BM, n0 = blockIdx.x * 128;
  const int li = lane & 15, lg = lane >> 4;

  // thread t stages elements t*8..t*8+7 of each 32-col tile (linear)
  const u16* Ag0 = A  + (size_t)(m0 + (t >> 2)) * K + (t & 3) * 8;
  const u16* Ag1 = Ag0 + (size_t)64 * K;
  const u16* Bg0 = Bt + (size_t)(n0 + (t >> 2)) * K + (t & 3) * 8;
  const u16* Bg1 = Bg0 + (size_t)64 * K;

  f32x4 acc[MI][4] = {};

  for (int k0 = 0; k0 < K; k0 += 32) {
    __syncthreads();                   // prev iter's LDS reads done
    gl16(Ag0 + k0, &As[t * 8]);
    if (LA == 2) gl16(Ag1 + k0, &As[t * 8 + 2048]);
    gl16(Bg0 + k0, &Bs[t * 8]);
    gl16(Bg1 + k0, &Bs[t * 8 + 2048]);
    __syncthreads();                   // drains vmcnt -> staging visible
    bf16x8 af[MI], bfr[4];
#pragma unroll
    for (int i = 0; i < MI; ++i)
      af[i] = *(const bf16x8*)&As[(wr*(MI*16) + i*16 + li)*32 + lg*8];
#pragma unroll
    for (int i = 0; i < 4; ++i)
      bfr[i] = *(const bf16x8*)&Bs[(wc*64 + i*16 + li)*32 + lg*8];
#pragma unroll
    for (int mi = 0; mi < MI; ++mi)
#pragma unroll
      for (int ni = 0; ni < 4; ++ni)
        acc[mi][ni] = __builtin_amdgcn_mfma_f32_16x16x32_bf16(
            af[mi], bfr[ni], acc[mi][ni], 0, 0, 0);
  }

  // C layout: col = lane&15, row = (lane>>4)*4 + reg
  const int crow = wr * (MI * 16) + lg * 4;
  const int ccol = wc * 64 + li;

  if (EPI == EPI_QKV) {
    const int which = n0 >> 10;                       // 0=q 1=k 2=v (uniform)
    const float* bias = which == 0 ? b0 : which == 1 ? b1 : b2;
    u16* outp        = which == 0 ? o0 : which == 1 ? o1 : o2;
    const int nn0 = n0 & 1023;
#pragma unroll
    for (int mi = 0; mi < MI; ++mi)
#pragma unroll
      for (int ni = 0; ni < 4; ++ni)
#pragma unroll
        for (int r = 0; r < 4; ++r) {
          const int gm = m0 + crow + mi * 16 + r;
          const int gc = nn0 + ccol + ni * 16;
          const float v = acc[mi][ni][r] + bias[gc];
          const int b_ = gm >> 11, s_ = gm & 2047;
          const int h_ = gc >> 6,  d_ = gc & 63;
          outp[((size_t)(b_ * 16 + h_) * 2048 + s_) * 64 + d_] = f2bf(v);
        }
  } else {
#pragma unroll
    for (int mi = 0; mi < MI; ++mi)
#pragma unroll
      for (int ni = 0; ni < 4; ++ni)
#pragma unroll
        for (int r = 0; r < 4; ++r) {
          const int gm = m0 + crow + mi * 16 + r;
          const int gn = n0 + ccol + ni * 16;
          const float v = acc[mi][ni][r] + b0[gn];
          if (EPI == EPI_RES) {
            const size_t o = (size_t)gm * N + gn;
            outf[o] = v + res[o];
          } else {
            const float gl = 0.5f * v * (1.0f + erff(v * 0.70710678f));
            o0[(size_t)gm * N + gn] = f2bf(gl);
          }
        }
  }
}

// ---------------------------------------------------------------------------
// Causal flash attention. q,k bf16 [BH,2048,64]; vt bf16 [BH,64,2048].
// Out bf16 [B,S,D]. 256 thr / 4 waves; 64 q-rows per block; KVBLK=128.
// K/Vt staged via global_load_lds with pre-swizzled source (rule 21):
//   Ks rows 128B, chunk ^= row&7;  Vt rows 256B, chunk ^= row&15.
// ---------------------------------------------------------------------------
__global__ __launch_bounds__(256)
void attn_fwd(const u16* __restrict__ qb, const u16* __restrict__ kb,
              const u16* __restrict__ vtb, u16* __restrict__ ob)
{
  __shared__ u16 Ks[128 * 64];      // [kv][d]  swizzled
  __shared__ u16 Vt[64 * 128];      // [d][kv]  swizzled
  __shared__ u16 Ps[4][16 * 64];    // per-wave P half-tile, swizzled
  const int t = threadIdx.x, w = t >> 6, lane = t & 63;
  const int li = lane & 15, lg = lane >> 4;
  const int bh = blockIdx.y;
  const int bx = blockIdx.x;
  const int qt = (bx & 1) ? (31 - (bx >> 1)) : (bx >> 1);  // balance pairing
  const int q0 = qt * 64;

  const size_t qrow = (size_t)bh * 2048 + q0 + w * 16 + li;
  const bf16x8 aq0 = *(const bf16x8*)(qb + qrow * 64 + lg * 8);
  const bf16x8 aq1 = *(const bf16x8*)(qb + qrow * 64 + lg * 8 + 32);

  f32x4 o[4] = {};
  float mrun[4], lrun[4];
#pragma unroll
  for (int r = 0; r < 4; ++r) { mrun[r] = -1e30f; lrun[r] = 0.0f; }

  const u16* kbase = kb  + (size_t)bh * 2048 * 64;
  const u16* vbase = vtb + (size_t)bh * 64 * 2048;
  const int ntile = (q0 + 191) >> 7;

  // staging source addresses (inverse-swizzled so LDS dest stays linear)
  const int kchunk = (t & 7)  ^ ((t >> 3) & 7);
  const int vchunk = (t & 15) ^ ((t >> 4) & 15);
  const u16* kg = kbase + (size_t)(t >> 3) * 64 + kchunk * 8;
  const u16* vg = vbase + (size_t)(t >> 4) * 2048 + vchunk * 8;

  for (int tk = 0; tk < ntile; ++tk) {
    const int kv0 = tk * 128;
    __syncthreads();                   // all waves done with prev tile
#pragma unroll
    for (int p = 0; p < 4; ++p) {
      gl16(kg + (size_t)(kv0 + p * 32) * 64, &Ks[t * 8 + p * 2048]);
      gl16(vg + kv0 + (size_t)p * 16 * 2048, &Vt[t * 8 + p * 2048]);
    }
    __syncthreads();                   // staging visible

    // S = Q K^T (16 q x 128 kv per wave)
    f32x4 s[8];
#pragma unroll
    for (int cf = 0; cf < 8; ++cf) {
      const int row = cf * 16 + li;
      const char* kc = (const char*)Ks + row * 128;
      const int sw = (row & 7) << 4;
      const bf16x8 bk0 = *(const bf16x8*)(kc + ((lg * 16)      ^ sw));
      const bf16x8 bk1 = *(const bf16x8*)(kc + ((lg * 16 + 64) ^ sw));
      f32x4 z = {};
      z = __builtin_amdgcn_mfma_f32_16x16x32_bf16(aq0, bk0, z, 0, 0, 0);
      z = __builtin_amdgcn_mfma_f32_16x16x32_bf16(aq1, bk1, z, 0, 0, 0);
      s[cf] = z;
    }
    const int row0 = q0 + w * 16 + lg * 4;
    const bool lastt = (tk == ntile - 1);
#pragma unroll
    for (int cf = 0; cf < 8; ++cf)
#pragma unroll
      for (int r = 0; r < 4; ++r) {
        float sv = s[cf][r] * 0.125f;
        if (lastt && (kv0 + cf * 16 + li > row0 + r)) sv = -1e30f;
        s[cf][r] = sv;
      }

    // online softmax (row stats across li within 16-lane groups)
    float pmax[4];
#pragma unroll
    for (int r = 0; r < 4; ++r) {
      float mx = s[0][r];
#pragma unroll
      for (int cf = 1; cf < 8; ++cf) mx = fmaxf(mx, s[cf][r]);
      pmax[r] = mx;
    }
#pragma unroll
    for (int d = 1; d < 16; d <<= 1)
#pragma unroll
      for (int r = 0; r < 4; ++r)
        pmax[r] = fmaxf(pmax[r], __shfl_xor(pmax[r], d, 64));
    float mnew[4], scl[4];
#pragma unroll
    for (int r = 0; r < 4; ++r) {
      mnew[r] = fmaxf(mrun[r], pmax[r]);
      scl[r]  = __expf(mrun[r] - mnew[r]);
    }
    float ps[4] = {0.f, 0.f, 0.f, 0.f};
#pragma unroll
    for (int cf = 0; cf < 8; ++cf)
#pragma unroll
      for (int r = 0; r < 4; ++r) {
        const float pv = __expf(s[cf][r] - mnew[r]);
        s[cf][r] = pv;                 // reuse regs: s now holds P
        ps[r] += pv;
      }
#pragma unroll
    for (int d = 1; d < 16; d <<= 1)
#pragma unroll
      for (int r = 0; r < 4; ++r)
        ps[r] += __shfl_xor(ps[r], d, 64);
#pragma unroll
    for (int r = 0; r < 4; ++r) {
      lrun[r] = lrun[r] * scl[r] + ps[r];
      mrun[r] = mnew[r];
    }
#pragma unroll
    for (int n = 0; n < 4; ++n)
#pragma unroll
      for (int r = 0; r < 4; ++r) o[n][r] *= scl[r];

    // PV in two kv-halves: P (C-layout) -> per-wave LDS -> A-frags.
    // Per-wave buffer: program order + in-order LDS => no barrier.
#pragma unroll
    for (int kh = 0; kh < 2; ++kh) {
#pragma unroll
      for (int cf2 = 0; cf2 < 4; ++cf2)
#pragma unroll
        for (int r = 0; r < 4; ++r) {
          const int prow = lg * 4 + r;
          const int pcolB = (cf2 * 16 + li) * 2;
          *(u16*)((char*)Ps[w] + prow * 128 + (pcolB ^ ((prow & 7) << 4))) =
              f2bf(s[kh * 4 + cf2][r]);
        }
#pragma unroll
      for (int ks = 0; ks < 2; ++ks) {
        const char* pc = (const char*)Ps[w] + li * 128;
        const bf16x8 ap =
            *(const bf16x8*)(pc + ((lg * 16 + ks * 64) ^ ((li & 7) << 4)));
#pragma unroll
        for (int n = 0; n < 4; ++n) {
          const int vrow = n * 16 + li;
          const char* vc = (const char*)Vt + vrow * 256;
          const int colB = lg * 16 + ks * 64 + kh * 128;
          const bf16x8 bv =
              *(const bf16x8*)(vc + (colB ^ ((vrow & 15) << 4)));
          o[n] = __builtin_amdgcn_mfma_f32_16x16x32_bf16(ap, bv, o[n], 0, 0, 0);
        }
      }
    }
  }

  float inv[4];
#pragma unroll
  for (int r = 0; r < 4; ++r) inv[r] = 1.0f / lrun[r];
  const int b_ = bh >> 4, h_ = bh & 15;
#pragma unroll
  for (int n = 0; n < 4; ++n)
#pragma unroll
    for (int r = 0; r < 4; ++r) {
      const int rowg = q0 + w * 16 + lg * 4 + r;
      ob[((size_t)b_ * 2048 + rowg) * 1024 + h_ * 64 + n * 16 + li] =
          f2bf(o[n][r] * inv[r]);
    }
}

// ---------------------------------------------------------------------------
extern "C" void kernel_launch(void* const* d_in, const int* in_sizes, int n_in,
                              void* d_out, int out_size, void* d_ws, size_t ws_size,
                              hipStream_t stream) {
  const float* x    = (const float*)d_in[0];
  const float* ln1g = (const float*)d_in[1];
  const float* ln1b = (const float*)d_in[2];
  const float* Wq   = (const float*)d_in[3];
  const float* bq   = (const float*)d_in[4];
  const float* Wk   = (const float*)d_in[5];
  const float* bk   = (const float*)d_in[6];
  const float* Wv   = (const float*)d_in[7];
  const float* bv   = (const float*)d_in[8];
  const float* Wo   = (const float*)d_in[9];
  const float* bo   = (const float*)d_in[10];
  const float* ln2g = (const float*)d_in[11];
  const float* ln2b = (const float*)d_in[12];
  const float* W1   = (const float*)d_in[13];
  const float* b1   = (const float*)d_in[14];
  const float* W2   = (const float*)d_in[15];
  const float* b2   = (const float*)d_in[16];

  char* ws = (char*)d_ws;
  const size_t MB = 1u << 20;           // total ws use: 80 MB
  u16*   hb   = (u16*)(ws + 0);         //  8 MB  LN out bf16 [4096,1024]
  u16*   Wqt  = (u16*)(ws + 8  * MB);   //  Wq^T,Wk^T,Wv^T contiguous (6 MB)
  u16*   Wkt  = (u16*)(ws + 10 * MB);
  u16*   Wvt  = (u16*)(ws + 12 * MB);
  u16*   Wot  = (u16*)(ws + 14 * MB);   //  2 MB
  u16*   W1t  = (u16*)(ws + 16 * MB);   //  8 MB  [4096][1024]
  u16*   W2t  = (u16*)(ws + 24 * MB);   //  8 MB  [1024][4096]
  u16*   qbuf = (u16*)(ws + 32 * MB);   //  8 MB  [B,H,S,DH]
  u16*   kbuf = (u16*)(ws + 40 * MB);
  u16*   vbuf = (u16*)(ws + 48 * MB);   //  8 MB; becomes aob after vtrans
  u16*   vtb  = (u16*)(ws + 56 * MB);   //  8 MB  [B,H,DH,S]
  float* x2   = (float*)(ws + 64 * MB); // 16 MB  fp32 residual
  u16*   aob  = vbuf;                   // attn out reuses vbuf region
  u16*   h2   = hb;                     // LN2 out reuses hb
  u16*   ff1  = qbuf;                   // 32 MB spans 32..64 (all dead by FF1)

  const dim3 blk(256);
  tconv<<<dim3(32, 32),  blk, 0, stream>>>(Wq, Wqt, 1024, 1024);
  tconv<<<dim3(32, 32),  blk, 0, stream>>>(Wk, Wkt, 1024, 1024);
  tconv<<<dim3(32, 32),  blk, 0, stream>>>(Wv, Wvt, 1024, 1024);
  tconv<<<dim3(32, 32),  blk, 0, stream>>>(Wo, Wot, 1024, 1024);
  tconv<<<dim3(128, 32), blk, 0, stream>>>(W1, W1t, 1024, 4096);
  tconv<<<dim3(32, 128), blk, 0, stream>>>(W2, W2t, 4096, 1024);

  ln_fwd<<<4096, blk, 0, stream>>>(x, ln1g, ln1b, hb);

  // fused QKV: Bt = [Wq^T;Wk^T;Wv^T] rows 0..3071
  gemm_bt<EPI_QKV, 128><<<dim3(24, 32), blk, 0, stream>>>(
      hb, Wqt, bq, bk, bv, nullptr, nullptr, qbuf, kbuf, vbuf, 3072, 1024);

  vtrans<<<dim3(64, 2, 32), blk, 0, stream>>>(vbuf, vtb);

  attn_fwd<<<dim3(32, 32), blk, 0, stream>>>(qbuf, kbuf, vtb, aob);

  gemm_bt<EPI_RES, 64><<<dim3(8, 64), blk, 0, stream>>>(
      aob, Wot, bo, nullptr, nullptr, x, x2, nullptr, nullptr, nullptr, 1024, 1024);

  ln_fwd<<<4096, blk, 0, stream>>>(x2, ln2g, ln2b, h2);

  gemm_bt<EPI_GELU, 128><<<dim3(32, 32), blk, 0, stream>>>(
      h2, W1t, b1, nullptr, nullptr, nullptr, nullptr, ff1, nullptr, nullptr, 4096, 1024);

  gemm_bt<EPI_RES, 64><<<dim3(8, 64), blk, 0, stream>>>(
      ff1, W2t, b2, nullptr, nullptr, x2, (float*)d_out, nullptr, nullptr, nullptr, 1024, 4096);
}

// Round 3
// 341.410 us; speedup vs baseline: 1.4580x; 1.0571x over previous
//
#include <hip/hip_runtime.h>
#include <cstdint>
#include <cstddef>

// Transformer block, B=2 S=2048 D=1024 H=16 DH=64 DFF=4096.
// Round 3: attention rebuilt — QBLK=128, 8 waves, double-buffered K/V with
// one barrier per KV-tile (stage overlapped with compute). GEMMs unchanged.

#define DEV static __device__ __forceinline__

typedef unsigned short u16;
typedef __bf16 bf16x8 __attribute__((ext_vector_type(8)));
typedef u16    u16x8  __attribute__((ext_vector_type(8)));
typedef u16    u16x4  __attribute__((ext_vector_type(4)));
typedef float  f32x4  __attribute__((ext_vector_type(4)));

DEV u16 f2bf(float f) {
  unsigned u = __builtin_bit_cast(unsigned, f);
  u += 0x7fffu + ((u >> 16) & 1u);   // RNE; inputs are finite
  return (u16)(u >> 16);
}

// async global->LDS, 16B per lane. LDS dest must be linear in lane order.
DEV void gl16(const void* g, void* l) {
  __builtin_amdgcn_global_load_lds(
      (const __attribute__((address_space(1))) unsigned*)g,
      (__attribute__((address_space(3))) unsigned*)l, 16, 0, 0);
}

// ---------------------------------------------------------------------------
// Weight transpose + fp32->bf16 convert:  in[R][C] fp32 -> out[C][R] bf16
// ---------------------------------------------------------------------------
__global__ __launch_bounds__(256)
void tconv(const float* __restrict__ in, u16* __restrict__ out, int R, int C)
{
  __shared__ float tile[32][33];
  const int tx = threadIdx.x & 31, ty = threadIdx.x >> 5;   // 32 x 8
  const int r0 = blockIdx.y * 32, c0 = blockIdx.x * 32;
#pragma unroll
  for (int i = 0; i < 4; ++i)
    tile[ty + 8*i][tx] = in[(size_t)(r0 + ty + 8*i) * C + c0 + tx];
  __syncthreads();
#pragma unroll
  for (int i = 0; i < 4; ++i)
    out[(size_t)(c0 + ty + 8*i) * R + r0 + tx] = f2bf(tile[tx][ty + 8*i]);
}

// ---------------------------------------------------------------------------
// V transpose bf16: in [BH][2048][64] -> out [BH][64][2048]
// ---------------------------------------------------------------------------
__global__ __launch_bounds__(256)
void vtrans(const u16* __restrict__ in, u16* __restrict__ out)
{
  __shared__ u16 tile[32][33];
  const int tx = threadIdx.x & 31, ty = threadIdx.x >> 5;
  const int s0 = blockIdx.x * 32, d0 = blockIdx.y * 32;
  const size_t base = (size_t)blockIdx.z * 2048 * 64;
#pragma unroll
  for (int i = 0; i < 4; ++i)
    tile[ty + 8*i][tx] = in[base + (size_t)(s0 + ty + 8*i) * 64 + d0 + tx];
  __syncthreads();
#pragma unroll
  for (int i = 0; i < 4; ++i)
    out[base + (size_t)(d0 + ty + 8*i) * 2048 + s0 + tx] = tile[tx][ty + 8*i];
}

// ---------------------------------------------------------------------------
// LayerNorm over D=1024, one block (256 threads) per row, out bf16
// ---------------------------------------------------------------------------
__global__ __launch_bounds__(256)
void ln_fwd(const float* __restrict__ x, const float* __restrict__ g,
            const float* __restrict__ b, u16* __restrict__ out)
{
  const int row = blockIdx.x, t = threadIdx.x;
  const float4 v = ((const float4*)(x + (size_t)row * 1024))[t];
  float s1 = v.x + v.y + v.z + v.w;
  float s2 = v.x*v.x + v.y*v.y + v.z*v.z + v.w*v.w;
#pragma unroll
  for (int d = 1; d < 64; d <<= 1) {
    s1 += __shfl_xor(s1, d, 64);
    s2 += __shfl_xor(s2, d, 64);
  }
  __shared__ float sh[8];
  const int w = t >> 6;
  if ((t & 63) == 0) { sh[w] = s1; sh[w + 4] = s2; }
  __syncthreads();
  s1 = sh[0] + sh[1] + sh[2] + sh[3];
  s2 = sh[4] + sh[5] + sh[6] + sh[7];
  const float mu  = s1 * (1.0f / 1024.0f);
  const float var = s2 * (1.0f / 1024.0f) - mu * mu;
  const float rs  = rsqrtf(var + 1e-5f);
  const float4 gv = ((const float4*)g)[t];
  const float4 bv = ((const float4*)b)[t];
  u16x4 o;
  o[0] = f2bf((v.x - mu) * rs * gv.x + bv.x);
  o[1] = f2bf((v.y - mu) * rs * gv.y + bv.y);
  o[2] = f2bf((v.z - mu) * rs * gv.z + bv.z);
  o[3] = f2bf((v.w - mu) * rs * gv.w + bv.w);
  *(u16x4*)(out + (size_t)row * 1024 + t * 4) = o;
}

// ---------------------------------------------------------------------------
// GEMM: C[M,N] = A[M,K](bf16) @ Bt[N,K]^T(bf16) + bias, fused epilogues.
// BMx128 tile, 4 waves (2x2), 16x16x32 bf16 MFMA, BK=32, global_load_lds.
// ---------------------------------------------------------------------------
#define EPI_QKV  0   // out bf16 [B,H,S,DH] x3 (fused QKV, N=3072)
#define EPI_RES  1   // out fp32 = acc + bias + res
#define EPI_GELU 2   // out bf16 = gelu(acc + bias)

template<int EPI, int BM>
__global__ __launch_bounds__(256)
void gemm_bt(const u16* __restrict__ A, const u16* __restrict__ Bt,
             const float* __restrict__ b0, const float* __restrict__ b1,
             const float* __restrict__ b2, const float* __restrict__ res,
             float* __restrict__ outf, u16* __restrict__ o0,
             u16* __restrict__ o1, u16* __restrict__ o2,
             int N, int K)
{
  constexpr int MI = BM / 32;          // 16-row A-frags per wave
  constexpr int LA = (BM * 32) / 2048; // gl16 rounds for A (1 or 2)
  __shared__ u16 As[BM * 32];
  __shared__ u16 Bs[128 * 32];
  const int t = threadIdx.x, lane = t & 63, w = t >> 6;
  const int wr = w >> 1, wc = w & 1;
  const int m0 = blockIdx.y * BM, n0 = blockIdx.x * 128;
  const int li = lane & 15, lg = lane >> 4;

  // thread t stages elements t*8..t*8+7 of each 32-col tile (linear)
  const u16* Ag0 = A  + (size_t)(m0 + (t >> 2)) * K + (t & 3) * 8;
  const u16* Ag1 = Ag0 + (size_t)64 * K;
  const u16* Bg0 = Bt + (size_t)(n0 + (t >> 2)) * K + (t & 3) * 8;
  const u16* Bg1 = Bg0 + (size_t)64 * K;

  f32x4 acc[MI][4] = {};

  for (int k0 = 0; k0 < K; k0 += 32) {
    __syncthreads();                   // prev iter's LDS reads done
    gl16(Ag0 + k0, &As[t * 8]);
    if (LA == 2) gl16(Ag1 + k0, &As[t * 8 + 2048]);
    gl16(Bg0 + k0, &Bs[t * 8]);
    gl16(Bg1 + k0, &Bs[t * 8 + 2048]);
    __syncthreads();                   // drains vmcnt -> staging visible
    bf16x8 af[MI], bfr[4];
#pragma unroll
    for (int i = 0; i < MI; ++i)
      af[i] = *(const bf16x8*)&As[(wr*(MI*16) + i*16 + li)*32 + lg*8];
#pragma unroll
    for (int i = 0; i < 4; ++i)
      bfr[i] = *(const bf16x8*)&Bs[(wc*64 + i*16 + li)*32 + lg*8];
#pragma unroll
    for (int mi = 0; mi < MI; ++mi)
#pragma unroll
      for (int ni = 0; ni < 4; ++ni)
        acc[mi][ni] = __builtin_amdgcn_mfma_f32_16x16x32_bf16(
            af[mi], bfr[ni], acc[mi][ni], 0, 0, 0);
  }

  // C layout: col = lane&15, row = (lane>>4)*4 + reg
  const int crow = wr * (MI * 16) + lg * 4;
  const int ccol = wc * 64 + li;

  if (EPI == EPI_QKV) {
    const int which = n0 >> 10;                       // 0=q 1=k 2=v (uniform)
    const float* bias = which == 0 ? b0 : which == 1 ? b1 : b2;
    u16* outp        = which == 0 ? o0 : which == 1 ? o1 : o2;
    const int nn0 = n0 & 1023;
#pragma unroll
    for (int mi = 0; mi < MI; ++mi)
#pragma unroll
      for (int ni = 0; ni < 4; ++ni)
#pragma unroll
        for (int r = 0; r < 4; ++r) {
          const int gm = m0 + crow + mi * 16 + r;
          const int gc = nn0 + ccol + ni * 16;
          const float v = acc[mi][ni][r] + bias[gc];
          const int b_ = gm >> 11, s_ = gm & 2047;
          const int h_ = gc >> 6,  d_ = gc & 63;
          outp[((size_t)(b_ * 16 + h_) * 2048 + s_) * 64 + d_] = f2bf(v);
        }
  } else {
#pragma unroll
    for (int mi = 0; mi < MI; ++mi)
#pragma unroll
      for (int ni = 0; ni < 4; ++ni)
#pragma unroll
        for (int r = 0; r < 4; ++r) {
          const int gm = m0 + crow + mi * 16 + r;
          const int gn = n0 + ccol + ni * 16;
          const float v = acc[mi][ni][r] + b0[gn];
          if (EPI == EPI_RES) {
            const size_t o = (size_t)gm * N + gn;
            outf[o] = v + res[o];
          } else {
            const float gl = 0.5f * v * (1.0f + erff(v * 0.70710678f));
            o0[(size_t)gm * N + gn] = f2bf(gl);
          }
        }
  }
}

// ---------------------------------------------------------------------------
// Causal flash attention. q,k bf16 [BH,2048,64]; vt bf16 [BH,64,2048].
// Out bf16 [B,S,D]. 512 thr / 8 waves; QBLK=128 q-rows/block; KVBLK=128.
// Double-buffered K/Vt via global_load_lds, ONE barrier per tile:
//   stage(next -> buf^1); compute(buf); __syncthreads()  (drains vmcnt).
// Swizzles (verified r2, conflicts=0): Ks rows 128B chunk^=row&7;
// Vt rows 256B chunk^=row&15; Ps rows 128B chunk^=row&7.
// ---------------------------------------------------------------------------
__global__ __launch_bounds__(512, 4)
void attn_fwd(const u16* __restrict__ qb, const u16* __restrict__ kb,
              const u16* __restrict__ vtb, u16* __restrict__ ob)
{
  __shared__ u16 Ks[2][128 * 64];   // [kv][d]  swizzled, dbuf
  __shared__ u16 Vt[2][64 * 128];   // [d][kv]  swizzled, dbuf
  __shared__ u16 Ps[8][16 * 64];    // per-wave P half-tile, swizzled
  const int t = threadIdx.x, w = t >> 6, lane = t & 63;
  const int li = lane & 15, lg = lane >> 4;
  const int bh = blockIdx.y;
  const int bx = blockIdx.x;                       // 0..15
  const int qt = (bx & 1) ? (15 - (bx >> 1)) : (bx >> 1);  // balance pairing
  const int q0 = qt * 128;

  const size_t qrow = (size_t)bh * 2048 + q0 + w * 16 + li;
  const bf16x8 aq0 = *(const bf16x8*)(qb + qrow * 64 + lg * 8);
  const bf16x8 aq1 = *(const bf16x8*)(qb + qrow * 64 + lg * 8 + 32);

  f32x4 o[4] = {};
  float mrun[4], lrun[4];
#pragma unroll
  for (int r = 0; r < 4; ++r) { mrun[r] = -1e30f; lrun[r] = 0.0f; }

  const u16* kbase = kb  + (size_t)bh * 2048 * 64;
  const u16* vbase = vtb + (size_t)bh * 64 * 2048;
  const int ntile = qt + 1;

  // staging source addresses (inverse-swizzled so LDS dest stays linear)
  // K round r: LDS row = t>>3 + r*64 (row&7 invariant); V: row = t>>4 + r*32.
  const int kchunk = (t & 7)  ^ ((t >> 3) & 7);
  const int vchunk = (t & 15) ^ ((t >> 4) & 15);
  const u16* kg = kbase + (size_t)(t >> 3) * 64 + kchunk * 8;
  const u16* vg = vbase + (size_t)(t >> 4) * 2048 + vchunk * 8;

#define STAGE(tk_, b_)                                              \
  {                                                                 \
    const int kv0s = (tk_) * 128;                                   \
    gl16(kg + (size_t)kv0s * 64,        &Ks[b_][t * 8]);            \
    gl16(kg + (size_t)(kv0s + 64) * 64, &Ks[b_][t * 8 + 4096]);     \
    gl16(vg + kv0s,                     &Vt[b_][t * 8]);            \
    gl16(vg + kv0s + (size_t)32 * 2048, &Vt[b_][t * 8 + 4096]);     \
  }

  STAGE(0, 0);
  __syncthreads();                     // tile 0 landed

  for (int tk = 0; tk < ntile; ++tk) {
    const int cur = tk & 1;
    const int kv0 = tk * 128;
    if (tk + 1 < ntile) STAGE(tk + 1, 1 - cur);   // overlaps with compute

    // S = Q K^T (16 q x 128 kv per wave)
    f32x4 s[8];
#pragma unroll
    for (int cf = 0; cf < 8; ++cf) {
      const int row = cf * 16 + li;
      const char* kc = (const char*)Ks[cur] + row * 128;
      const int sw = (row & 7) << 4;
      const bf16x8 bk0 = *(const bf16x8*)(kc + ((lg * 16)      ^ sw));
      const bf16x8 bk1 = *(const bf16x8*)(kc + ((lg * 16 + 64) ^ sw));
      f32x4 z = {};
      z = __builtin_amdgcn_mfma_f32_16x16x32_bf16(aq0, bk0, z, 0, 0, 0);
      z = __builtin_amdgcn_mfma_f32_16x16x32_bf16(aq1, bk1, z, 0, 0, 0);
      s[cf] = z;
    }
    const int row0 = q0 + w * 16 + lg * 4;
    const bool lastt = (tk == ntile - 1);
#pragma unroll
    for (int cf = 0; cf < 8; ++cf)
#pragma unroll
      for (int r = 0; r < 4; ++r) {
        float sv = s[cf][r] * 0.125f;
        if (lastt && (kv0 + cf * 16 + li > row0 + r)) sv = -1e30f;
        s[cf][r] = sv;
      }

    // online softmax (row stats across li within 16-lane groups)
    float pmax[4];
#pragma unroll
    for (int r = 0; r < 4; ++r) {
      float mx = s[0][r];
#pragma unroll
      for (int cf = 1; cf < 8; ++cf) mx = fmaxf(mx, s[cf][r]);
      pmax[r] = mx;
    }
#pragma unroll
    for (int d = 1; d < 16; d <<= 1)
#pragma unroll
      for (int r = 0; r < 4; ++r)
        pmax[r] = fmaxf(pmax[r], __shfl_xor(pmax[r], d, 64));
    float mnew[4], scl[4];
#pragma unroll
    for (int r = 0; r < 4; ++r) {
      mnew[r] = fmaxf(mrun[r], pmax[r]);
      scl[r]  = __expf(mrun[r] - mnew[r]);
    }
    float ps[4] = {0.f, 0.f, 0.f, 0.f};
#pragma unroll
    for (int cf = 0; cf < 8; ++cf)
#pragma unroll
      for (int r = 0; r < 4; ++r) {
        const float pv = __expf(s[cf][r] - mnew[r]);
        s[cf][r] = pv;                 // s now holds P
        ps[r] += pv;
      }
#pragma unroll
    for (int d = 1; d < 16; d <<= 1)
#pragma unroll
      for (int r = 0; r < 4; ++r)
        ps[r] += __shfl_xor(ps[r], d, 64);
#pragma unroll
    for (int r = 0; r < 4; ++r) {
      lrun[r] = lrun[r] * scl[r] + ps[r];
      mrun[r] = mnew[r];
    }
#pragma unroll
    for (int n = 0; n < 4; ++n)
#pragma unroll
      for (int r = 0; r < 4; ++r) o[n][r] *= scl[r];

    // PV in two kv-halves: P (C-layout) -> per-wave LDS -> A-frags.
    // Per-wave buffer: program order + in-order LDS => no barrier.
#pragma unroll
    for (int kh = 0; kh < 2; ++kh) {
#pragma unroll
      for (int cf2 = 0; cf2 < 4; ++cf2)
#pragma unroll
        for (int r = 0; r < 4; ++r) {
          const int prow = lg * 4 + r;
          const int pcolB = (cf2 * 16 + li) * 2;
          *(u16*)((char*)Ps[w] + prow * 128 + (pcolB ^ ((prow & 7) << 4))) =
              f2bf(s[kh * 4 + cf2][r]);
        }
#pragma unroll
      for (int ks = 0; ks < 2; ++ks) {
        const char* pc = (const char*)Ps[w] + li * 128;
        const bf16x8 ap =
            *(const bf16x8*)(pc + ((lg * 16 + ks * 64) ^ ((li & 7) << 4)));
#pragma unroll
        for (int n = 0; n < 4; ++n) {
          const int vrow = n * 16 + li;
          const char* vc = (const char*)Vt[cur] + vrow * 256;
          const int colB = lg * 16 + ks * 64 + kh * 128;
          const bf16x8 bv =
              *(const bf16x8*)(vc + (colB ^ ((vrow & 15) << 4)));
          o[n] = __builtin_amdgcn_mfma_f32_16x16x32_bf16(ap, bv, o[n], 0, 0, 0);
        }
      }
    }

    __syncthreads();   // drains vmcnt (next tile landed) + LDS reads done
  }
#undef STAGE

  float inv[4];
#pragma unroll
  for (int r = 0; r < 4; ++r) inv[r] = 1.0f / lrun[r];
  const int b_ = bh >> 4, h_ = bh & 15;
#pragma unroll
  for (int n = 0; n < 4; ++n)
#pragma unroll
    for (int r = 0; r < 4; ++r) {
      const int rowg = q0 + w * 16 + lg * 4 + r;
      ob[((size_t)b_ * 2048 + rowg) * 1024 + h_ * 64 + n * 16 + li] =
          f2bf(o[n][r] * inv[r]);
    }
}

// ---------------------------------------------------------------------------
extern "C" void kernel_launch(void* const* d_in, const int* in_sizes, int n_in,
                              void* d_out, int out_size, void* d_ws, size_t ws_size,
                              hipStream_t stream) {
  const float* x    = (const float*)d_in[0];
  const float* ln1g = (const float*)d_in[1];
  const float* ln1b = (const float*)d_in[2];
  const float* Wq   = (const float*)d_in[3];
  const float* bq   = (const float*)d_in[4];
  const float* Wk   = (const float*)d_in[5];
  const float* bk   = (const float*)d_in[6];
  const float* Wv   = (const float*)d_in[7];
  const float* bv   = (const float*)d_in[8];
  const float* Wo   = (const float*)d_in[9];
  const float* bo   = (const float*)d_in[10];
  const float* ln2g = (const float*)d_in[11];
  const float* ln2b = (const float*)d_in[12];
  const float* W1   = (const float*)d_in[13];
  const float* b1   = (const float*)d_in[14];
  const float* W2   = (const float*)d_in[15];
  const float* b2   = (const float*)d_in[16];

  char* ws = (char*)d_ws;
  const size_t MB = 1u << 20;           // total ws use: 80 MB
  u16*   hb   = (u16*)(ws + 0);         //  8 MB  LN out bf16 [4096,1024]
  u16*   Wqt  = (u16*)(ws + 8  * MB);   //  Wq^T,Wk^T,Wv^T contiguous (6 MB)
  u16*   Wkt  = (u16*)(ws + 10 * MB);
  u16*   Wvt  = (u16*)(ws + 12 * MB);
  u16*   Wot  = (u16*)(ws + 14 * MB);   //  2 MB
  u16*   W1t  = (u16*)(ws + 16 * MB);   //  8 MB  [4096][1024]
  u16*   W2t  = (u16*)(ws + 24 * MB);   //  8 MB  [1024][4096]
  u16*   qbuf = (u16*)(ws + 32 * MB);   //  8 MB  [B,H,S,DH]
  u16*   kbuf = (u16*)(ws + 40 * MB);
  u16*   vbuf = (u16*)(ws + 48 * MB);   //  8 MB; becomes aob after vtrans
  u16*   vtb  = (u16*)(ws + 56 * MB);   //  8 MB  [B,H,DH,S]
  float* x2   = (float*)(ws + 64 * MB); // 16 MB  fp32 residual
  u16*   aob  = vbuf;                   // attn out reuses vbuf region
  u16*   h2   = hb;                     // LN2 out reuses hb
  u16*   ff1  = qbuf;                   // 32 MB spans 32..64 (all dead by FF1)

  const dim3 blk(256);
  tconv<<<dim3(32, 32),  blk, 0, stream>>>(Wq, Wqt, 1024, 1024);
  tconv<<<dim3(32, 32),  blk, 0, stream>>>(Wk, Wkt, 1024, 1024);
  tconv<<<dim3(32, 32),  blk, 0, stream>>>(Wv, Wvt, 1024, 1024);
  tconv<<<dim3(32, 32),  blk, 0, stream>>>(Wo, Wot, 1024, 1024);
  tconv<<<dim3(128, 32), blk, 0, stream>>>(W1, W1t, 1024, 4096);
  tconv<<<dim3(32, 128), blk, 0, stream>>>(W2, W2t, 4096, 1024);

  ln_fwd<<<4096, blk, 0, stream>>>(x, ln1g, ln1b, hb);

  // fused QKV: Bt = [Wq^T;Wk^T;Wv^T] rows 0..3071
  gemm_bt<EPI_QKV, 128><<<dim3(24, 32), blk, 0, stream>>>(
      hb, Wqt, bq, bk, bv, nullptr, nullptr, qbuf, kbuf, vbuf, 3072, 1024);

  vtrans<<<dim3(64, 2, 32), blk, 0, stream>>>(vbuf, vtb);

  attn_fwd<<<dim3(16, 32), dim3(512), 0, stream>>>(qbuf, kbuf, vtb, aob);

  gemm_bt<EPI_RES, 64><<<dim3(8, 64), blk, 0, stream>>>(
      aob, Wot, bo, nullptr, nullptr, x, x2, nullptr, nullptr, nullptr, 1024, 1024);

  ln_fwd<<<4096, blk, 0, stream>>>(x2, ln2g, ln2b, h2);

  gemm_bt<EPI_GELU, 128><<<dim3(32, 32), blk, 0, stream>>>(
      h2, W1t, b1, nullptr, nullptr, nullptr, nullptr, ff1, nullptr, nullptr, 4096, 1024);

  gemm_bt<EPI_RES, 64><<<dim3(8, 64), blk, 0, stream>>>(
      ff1, W2t, b2, nullptr, nullptr, x2, (float*)d_out, nullptr, nullptr, nullptr, 1024, 4096);
}

// Round 4
// 300.575 us; speedup vs baseline: 1.6561x; 1.1359x over previous
//
#include <hip/hip_runtime.h>
#include <cstdint>
#include <cstddef>

// Transformer block, B=2 S=2048 D=1024 H=16 DH=64 DFF=4096.
// Round 4: BK=64 for skinny GEMMs (Wo/FF2), V^T folded into QKV epilogue
// (vtrans deleted), exp2-domain softmax w/ prescaled Q + defer-max + setprio,
// exp2-based GELU, fused square-weight transposes.

#define DEV static __device__ __forceinline__

typedef unsigned short u16;
typedef __bf16 bf16x8 __attribute__((ext_vector_type(8)));
typedef u16    u16x8  __attribute__((ext_vector_type(8)));
typedef u16    u16x4  __attribute__((ext_vector_type(4)));
typedef float  f32x4  __attribute__((ext_vector_type(4)));

#define AEXP2(x) __builtin_amdgcn_exp2f(x)

DEV u16 f2bf(float f) {
  unsigned u = __builtin_bit_cast(unsigned, f);
  u += 0x7fffu + ((u >> 16) & 1u);   // RNE; inputs are finite
  return (u16)(u >> 16);
}

// async global->LDS, 16B per lane. LDS dest must be linear in lane order.
DEV void gl16(const void* g, void* l) {
  __builtin_amdgcn_global_load_lds(
      (const __attribute__((address_space(1))) unsigned*)g,
      (__attribute__((address_space(3))) unsigned*)l, 16, 0, 0);
}

// ---------------------------------------------------------------------------
// Weight transpose + fp32->bf16 convert:  in[R][C] fp32 -> out[C][R] bf16
// ---------------------------------------------------------------------------
__global__ __launch_bounds__(256)
void tconv(const float* __restrict__ in, u16* __restrict__ out, int R, int C)
{
  __shared__ float tile[32][33];
  const int tx = threadIdx.x & 31, ty = threadIdx.x >> 5;   // 32 x 8
  const int r0 = blockIdx.y * 32, c0 = blockIdx.x * 32;
#pragma unroll
  for (int i = 0; i < 4; ++i)
    tile[ty + 8*i][tx] = in[(size_t)(r0 + ty + 8*i) * C + c0 + tx];
  __syncthreads();
#pragma unroll
  for (int i = 0; i < 4; ++i)
    out[(size_t)(c0 + ty + 8*i) * R + r0 + tx] = f2bf(tile[tx][ty + 8*i]);
}

// four 1024x1024 transposes in one dispatch (blockIdx.z selects weight)
__global__ __launch_bounds__(256)
void tconv4(const float* __restrict__ w0, const float* __restrict__ w1,
            const float* __restrict__ w2, const float* __restrict__ w3,
            u16* __restrict__ q0, u16* __restrict__ q1,
            u16* __restrict__ q2, u16* __restrict__ q3)
{
  __shared__ float tile[32][33];
  const int z = blockIdx.z;
  const float* in = z == 0 ? w0 : z == 1 ? w1 : z == 2 ? w2 : w3;
  u16* out       = z == 0 ? q0 : z == 1 ? q1 : z == 2 ? q2 : q3;
  const int tx = threadIdx.x & 31, ty = threadIdx.x >> 5;
  const int r0 = blockIdx.y * 32, c0 = blockIdx.x * 32;
#pragma unroll
  for (int i = 0; i < 4; ++i)
    tile[ty + 8*i][tx] = in[(size_t)(r0 + ty + 8*i) * 1024 + c0 + tx];
  __syncthreads();
#pragma unroll
  for (int i = 0; i < 4; ++i)
    out[(size_t)(c0 + ty + 8*i) * 1024 + r0 + tx] = f2bf(tile[tx][ty + 8*i]);
}

// ---------------------------------------------------------------------------
// LayerNorm over D=1024, one block (256 threads) per row, out bf16
// ---------------------------------------------------------------------------
__global__ __launch_bounds__(256)
void ln_fwd(const float* __restrict__ x, const float* __restrict__ g,
            const float* __restrict__ b, u16* __restrict__ out)
{
  const int row = blockIdx.x, t = threadIdx.x;
  const float4 v = ((const float4*)(x + (size_t)row * 1024))[t];
  float s1 = v.x + v.y + v.z + v.w;
  float s2 = v.x*v.x + v.y*v.y + v.z*v.z + v.w*v.w;
#pragma unroll
  for (int d = 1; d < 64; d <<= 1) {
    s1 += __shfl_xor(s1, d, 64);
    s2 += __shfl_xor(s2, d, 64);
  }
  __shared__ float sh[8];
  const int w = t >> 6;
  if ((t & 63) == 0) { sh[w] = s1; sh[w + 4] = s2; }
  __syncthreads();
  s1 = sh[0] + sh[1] + sh[2] + sh[3];
  s2 = sh[4] + sh[5] + sh[6] + sh[7];
  const float mu  = s1 * (1.0f / 1024.0f);
  const float var = s2 * (1.0f / 1024.0f) - mu * mu;
  const float rs  = rsqrtf(var + 1e-5f);
  const float4 gv = ((const float4*)g)[t];
  const float4 bv = ((const float4*)b)[t];
  u16x4 o;
  o[0] = f2bf((v.x - mu) * rs * gv.x + bv.x);
  o[1] = f2bf((v.y - mu) * rs * gv.y + bv.y);
  o[2] = f2bf((v.z - mu) * rs * gv.z + bv.z);
  o[3] = f2bf((v.w - mu) * rs * gv.w + bv.w);
  *(u16x4*)(out + (size_t)row * 1024 + t * 4) = o;
}

// ---------------------------------------------------------------------------
// GEMM: C[M,N] = A[M,K](bf16) @ Bt[N,K]^T(bf16) + bias, fused epilogues.
// BMx128 tile, 4 waves (2x2), 16x16x32 bf16 MFMA, BK-step, global_load_lds.
// ---------------------------------------------------------------------------
#define EPI_QKV  0   // out bf16: Q prescaled [B,H,S,DH]; K [B,H,S,DH]; V^T [B,H,DH,S]
#define EPI_RES  1   // out fp32 = acc + bias + res
#define EPI_GELU 2   // out bf16 = gelu(acc + bias)

#define QSCALE 0.180421f   // 0.125 * log2(e): softmax runs in exp2 domain

template<int EPI, int BM, int BK>
__global__ __launch_bounds__(256)
void gemm_bt(const u16* __restrict__ A, const u16* __restrict__ Bt,
             const float* __restrict__ b0, const float* __restrict__ b1,
             const float* __restrict__ b2, const float* __restrict__ res,
             float* __restrict__ outf, u16* __restrict__ o0,
             u16* __restrict__ o1, u16* __restrict__ o2,
             int N, int K)
{
  constexpr int MI  = BM / 32;           // 16-row A-frags per wave
  constexpr int TPR = BK / 8;            // staging threads per row
  constexpr int RPR = 256 / TPR;         // rows per gl16 round
  constexpr int RA  = (BM * BK) / 2048;  // A gl16 rounds
  constexpr int RB  = (128 * BK) / 2048; // B gl16 rounds
  __shared__ u16 As[BM * BK];
  __shared__ u16 Bs[128 * BK];
  const int t = threadIdx.x, lane = t & 63, w = t >> 6;
  const int wr = w >> 1, wc = w & 1;
  const int m0 = blockIdx.y * BM, n0 = blockIdx.x * 128;
  const int li = lane & 15, lg = lane >> 4;

  const u16* Ag = A  + (size_t)(m0 + t / TPR) * K + (t % TPR) * 8;
  const u16* Bg = Bt + (size_t)(n0 + t / TPR) * K + (t % TPR) * 8;

  f32x4 acc[MI][4] = {};

  for (int k0 = 0; k0 < K; k0 += BK) {
    __syncthreads();                   // prev iter's LDS reads done
#pragma unroll
    for (int p = 0; p < RA; ++p)
      gl16(Ag + k0 + (size_t)p * RPR * K, &As[t * 8 + p * 2048]);
#pragma unroll
    for (int p = 0; p < RB; ++p)
      gl16(Bg + k0 + (size_t)p * RPR * K, &Bs[t * 8 + p * 2048]);
    __syncthreads();                   // drains vmcnt -> staging visible
#pragma unroll
    for (int ks = 0; ks < BK / 32; ++ks) {
      bf16x8 af[MI], bfr[4];
#pragma unroll
      for (int i = 0; i < MI; ++i)
        af[i] = *(const bf16x8*)&As[(wr*(MI*16) + i*16 + li)*BK + ks*32 + lg*8];
#pragma unroll
      for (int i = 0; i < 4; ++i)
        bfr[i] = *(const bf16x8*)&Bs[(wc*64 + i*16 + li)*BK + ks*32 + lg*8];
#pragma unroll
      for (int mi = 0; mi < MI; ++mi)
#pragma unroll
        for (int ni = 0; ni < 4; ++ni)
          acc[mi][ni] = __builtin_amdgcn_mfma_f32_16x16x32_bf16(
              af[mi], bfr[ni], acc[mi][ni], 0, 0, 0);
    }
  }

  // C layout: col = lane&15, row = (lane>>4)*4 + reg
  const int crow = wr * (MI * 16) + lg * 4;
  const int ccol = wc * 64 + li;

  if (EPI == EPI_QKV) {
    const int which = n0 >> 10;                       // 0=q 1=k 2=v (uniform)
    const float* bias = which == 0 ? b0 : which == 1 ? b1 : b2;
    const int nn0 = n0 & 1023;
    if (which == 2) {
      // V: write transposed [BH][64][2048]; r -> consecutive s => u16x4 store
#pragma unroll
      for (int mi = 0; mi < MI; ++mi)
#pragma unroll
        for (int ni = 0; ni < 4; ++ni) {
          const int gm0 = m0 + crow + mi * 16;        // r=0 row (4-aligned)
          const int b_ = gm0 >> 11, s_ = gm0 & 2047;
          const int gc = nn0 + ccol + ni * 16;
          const int h_ = gc >> 6, d_ = gc & 63;
          u16x4 pk;
#pragma unroll
          for (int r = 0; r < 4; ++r) pk[r] = f2bf(acc[mi][ni][r] + bias[gc]);
          *(u16x4*)(o2 + ((size_t)(b_ * 16 + h_) * 64 + d_) * 2048 + s_) = pk;
        }
    } else {
      u16* outp = which == 0 ? o0 : o1;
      const float sc = which == 0 ? QSCALE : 1.0f;
#pragma unroll
      for (int mi = 0; mi < MI; ++mi)
#pragma unroll
        for (int ni = 0; ni < 4; ++ni)
#pragma unroll
          for (int r = 0; r < 4; ++r) {
            const int gm = m0 + crow + mi * 16 + r;
            const int gc = nn0 + ccol + ni * 16;
            const float v = (acc[mi][ni][r] + bias[gc]) * sc;
            const int b_ = gm >> 11, s_ = gm & 2047;
            const int h_ = gc >> 6,  d_ = gc & 63;
            outp[((size_t)(b_ * 16 + h_) * 2048 + s_) * 64 + d_] = f2bf(v);
          }
    }
  } else {
#pragma unroll
    for (int mi = 0; mi < MI; ++mi)
#pragma unroll
      for (int ni = 0; ni < 4; ++ni)
#pragma unroll
        for (int r = 0; r < 4; ++r) {
          const int gm = m0 + crow + mi * 16 + r;
          const int gn = n0 + ccol + ni * 16;
          const float v = acc[mi][ni][r] + b0[gn];
          if (EPI == EPI_RES) {
            const size_t o = (size_t)gm * N + gn;
            outf[o] = v + res[o];
          } else {
            // gelu via tanh approx in exp2 domain (err ~1e-3 << bf16 tol)
            const float y = 0.7978845608f * (v + 0.044715f * v * v * v);
            const float e = AEXP2(fminf(y * 2.8853900818f, 80.0f));
            const float gl = v * e * __builtin_amdgcn_rcpf(e + 1.0f);
            o0[(size_t)gm * N + gn] = f2bf(gl);
          }
        }
  }
}

// ---------------------------------------------------------------------------
// Causal flash attention. q (prescaled by 0.125*log2e), k bf16 [BH,2048,64];
// vt bf16 [BH,64,2048]. Out bf16 [B,S,D]. 512 thr / 8 waves; QBLK=KVBLK=128.
// Double-buffered K/Vt via global_load_lds, ONE barrier per tile.
// Softmax in exp2 domain with defer-max (THR=11.5 log2-units).
// Swizzles (verified, conflicts=0): Ks rows 128B chunk^=row&7;
// Vt rows 256B chunk^=row&15; Ps rows 128B chunk^=row&7.
// ---------------------------------------------------------------------------
__global__ __launch_bounds__(512, 4)
void attn_fwd(const u16* __restrict__ qb, const u16* __restrict__ kb,
              const u16* __restrict__ vtb, u16* __restrict__ ob)
{
  __shared__ u16 Ks[2][128 * 64];   // [kv][d]  swizzled, dbuf
  __shared__ u16 Vt[2][64 * 128];   // [d][kv]  swizzled, dbuf
  __shared__ u16 Ps[8][16 * 64];    // per-wave P half-tile, swizzled
  const int t = threadIdx.x, w = t >> 6, lane = t & 63;
  const int li = lane & 15, lg = lane >> 4;
  const int bh = blockIdx.y;
  const int bx = blockIdx.x;                       // 0..15
  const int qt = (bx & 1) ? (15 - (bx >> 1)) : (bx >> 1);  // balance pairing
  const int q0 = qt * 128;

  const size_t qrow = (size_t)bh * 2048 + q0 + w * 16 + li;
  const bf16x8 aq0 = *(const bf16x8*)(qb + qrow * 64 + lg * 8);
  const bf16x8 aq1 = *(const bf16x8*)(qb + qrow * 64 + lg * 8 + 32);

  f32x4 o[4] = {};
  float mrun[4], lrun[4];
#pragma unroll
  for (int r = 0; r < 4; ++r) { mrun[r] = -1e30f; lrun[r] = 0.0f; }

  const u16* kbase = kb  + (size_t)bh * 2048 * 64;
  const u16* vbase = vtb + (size_t)bh * 64 * 2048;
  const int ntile = qt + 1;

  // staging source addresses (inverse-swizzled so LDS dest stays linear)
  const int kchunk = (t & 7)  ^ ((t >> 3) & 7);
  const int vchunk = (t & 15) ^ ((t >> 4) & 15);
  const u16* kg = kbase + (size_t)(t >> 3) * 64 + kchunk * 8;
  const u16* vg = vbase + (size_t)(t >> 4) * 2048 + vchunk * 8;

#define STAGE(tk_, b_)                                              \
  {                                                                 \
    const int kv0s = (tk_) * 128;                                   \
    gl16(kg + (size_t)kv0s * 64,        &Ks[b_][t * 8]);            \
    gl16(kg + (size_t)(kv0s + 64) * 64, &Ks[b_][t * 8 + 4096]);     \
    gl16(vg + kv0s,                     &Vt[b_][t * 8]);            \
    gl16(vg + kv0s + (size_t)32 * 2048, &Vt[b_][t * 8 + 4096]);     \
  }

  STAGE(0, 0);
  __syncthreads();                     // tile 0 landed

  for (int tk = 0; tk < ntile; ++tk) {
    const int cur = tk & 1;
    const int kv0 = tk * 128;
    if (tk + 1 < ntile) STAGE(tk + 1, 1 - cur);   // overlaps with compute

    // S = Q K^T (exp2-domain, 16 q x 128 kv per wave)
    f32x4 s[8];
    __builtin_amdgcn_s_setprio(1);
#pragma unroll
    for (int cf = 0; cf < 8; ++cf) {
      const int row = cf * 16 + li;
      const char* kc = (const char*)Ks[cur] + row * 128;
      const int sw = (row & 7) << 4;
      const bf16x8 bk0 = *(const bf16x8*)(kc + ((lg * 16)      ^ sw));
      const bf16x8 bk1 = *(const bf16x8*)(kc + ((lg * 16 + 64) ^ sw));
      f32x4 z = {};
      z = __builtin_amdgcn_mfma_f32_16x16x32_bf16(aq0, bk0, z, 0, 0, 0);
      z = __builtin_amdgcn_mfma_f32_16x16x32_bf16(aq1, bk1, z, 0, 0, 0);
      s[cf] = z;
    }
    __builtin_amdgcn_s_setprio(0);
    const int row0 = q0 + w * 16 + lg * 4;
    if (tk == ntile - 1) {             // causal mask, last tile only
#pragma unroll
      for (int cf = 0; cf < 8; ++cf)
#pragma unroll
        for (int r = 0; r < 4; ++r)
          if (kv0 + cf * 16 + li > row0 + r) s[cf][r] = -1e30f;
    }

    // online softmax (row stats across li within 16-lane groups)
    float pmax[4];
#pragma unroll
    for (int r = 0; r < 4; ++r) {
      float mx = s[0][r];
#pragma unroll
      for (int cf = 1; cf < 8; ++cf) mx = fmaxf(mx, s[cf][r]);
      pmax[r] = mx;
    }
#pragma unroll
    for (int d = 1; d < 16; d <<= 1)
#pragma unroll
      for (int r = 0; r < 4; ++r)
        pmax[r] = fmaxf(pmax[r], __shfl_xor(pmax[r], d, 64));

    // defer-max: only rescale when the running max grew materially
    bool need = false;
#pragma unroll
    for (int r = 0; r < 4; ++r) need = need || (pmax[r] > mrun[r] + 11.5f);
    if (__any((int)need)) {
#pragma unroll
      for (int r = 0; r < 4; ++r) {
        const float mnew = fmaxf(mrun[r], pmax[r]);
        const float scl  = AEXP2(mrun[r] - mnew);
        lrun[r] *= scl;
#pragma unroll
        for (int n = 0; n < 4; ++n) o[n][r] *= scl;
        mrun[r] = mnew;
      }
    }
    float ps[4] = {0.f, 0.f, 0.f, 0.f};
#pragma unroll
    for (int cf = 0; cf < 8; ++cf)
#pragma unroll
      for (int r = 0; r < 4; ++r) {
        const float pv = AEXP2(s[cf][r] - mrun[r]);
        s[cf][r] = pv;                 // s now holds P
        ps[r] += pv;
      }
#pragma unroll
    for (int d = 1; d < 16; d <<= 1)
#pragma unroll
      for (int r = 0; r < 4; ++r)
        ps[r] += __shfl_xor(ps[r], d, 64);
#pragma unroll
    for (int r = 0; r < 4; ++r) lrun[r] += ps[r];

    // PV in two kv-halves: P (C-layout) -> per-wave LDS -> A-frags.
    // Per-wave buffer: program order + in-order LDS => no barrier.
#pragma unroll
    for (int kh = 0; kh < 2; ++kh) {
#pragma unroll
      for (int cf2 = 0; cf2 < 4; ++cf2)
#pragma unroll
        for (int r = 0; r < 4; ++r) {
          const int prow = lg * 4 + r;
          const int pcolB = (cf2 * 16 + li) * 2;
          *(u16*)((char*)Ps[w] + prow * 128 + (pcolB ^ ((prow & 7) << 4))) =
              f2bf(s[kh * 4 + cf2][r]);
        }
      __builtin_amdgcn_s_setprio(1);
#pragma unroll
      for (int ks = 0; ks < 2; ++ks) {
        const char* pc = (const char*)Ps[w] + li * 128;
        const bf16x8 ap =
            *(const bf16x8*)(pc + ((lg * 16 + ks * 64) ^ ((li & 7) << 4)));
#pragma unroll
        for (int n = 0; n < 4; ++n) {
          const int vrow = n * 16 + li;
          const char* vc = (const char*)Vt[cur] + vrow * 256;
          const int colB = lg * 16 + ks * 64 + kh * 128;
          const bf16x8 bv =
              *(const bf16x8*)(vc + (colB ^ ((vrow & 15) << 4)));
          o[n] = __builtin_amdgcn_mfma_f32_16x16x32_bf16(ap, bv, o[n], 0, 0, 0);
        }
      }
      __builtin_amdgcn_s_setprio(0);
    }

    __syncthreads();   // drains vmcnt (next tile landed) + LDS reads done
  }
#undef STAGE

  float inv[4];
#pragma unroll
  for (int r = 0; r < 4; ++r) inv[r] = __builtin_amdgcn_rcpf(lrun[r]);
  const int b_ = bh >> 4, h_ = bh & 15;
#pragma unroll
  for (int n = 0; n < 4; ++n)
#pragma unroll
    for (int r = 0; r < 4; ++r) {
      const int rowg = q0 + w * 16 + lg * 4 + r;
      ob[((size_t)b_ * 2048 + rowg) * 1024 + h_ * 64 + n * 16 + li] =
          f2bf(o[n][r] * inv[r]);
    }
}

// ---------------------------------------------------------------------------
extern "C" void kernel_launch(void* const* d_in, const int* in_sizes, int n_in,
                              void* d_out, int out_size, void* d_ws, size_t ws_size,
                              hipStream_t stream) {
  const float* x    = (const float*)d_in[0];
  const float* ln1g = (const float*)d_in[1];
  const float* ln1b = (const float*)d_in[2];
  const float* Wq   = (const float*)d_in[3];
  const float* bq   = (const float*)d_in[4];
  const float* Wk   = (const float*)d_in[5];
  const float* bk   = (const float*)d_in[6];
  const float* Wv   = (const float*)d_in[7];
  const float* bv   = (const float*)d_in[8];
  const float* Wo   = (const float*)d_in[9];
  const float* bo   = (const float*)d_in[10];
  const float* ln2g = (const float*)d_in[11];
  const float* ln2b = (const float*)d_in[12];
  const float* W1   = (const float*)d_in[13];
  const float* b1   = (const float*)d_in[14];
  const float* W2   = (const float*)d_in[15];
  const float* b2   = (const float*)d_in[16];

  char* ws = (char*)d_ws;
  const size_t MB = 1u << 20;           // total ws use: 80 MB
  u16*   hb   = (u16*)(ws + 0);         //  8 MB  LN out bf16 [4096,1024]
  u16*   Wqt  = (u16*)(ws + 8  * MB);   //  Wq^T,Wk^T,Wv^T contiguous (6 MB)
  u16*   Wkt  = (u16*)(ws + 10 * MB);
  u16*   Wvt  = (u16*)(ws + 12 * MB);
  u16*   Wot  = (u16*)(ws + 14 * MB);   //  2 MB
  u16*   W1t  = (u16*)(ws + 16 * MB);   //  8 MB  [4096][1024]
  u16*   W2t  = (u16*)(ws + 24 * MB);   //  8 MB  [1024][4096]
  u16*   qbuf = (u16*)(ws + 32 * MB);   //  8 MB  [B,H,S,DH] (prescaled)
  u16*   kbuf = (u16*)(ws + 40 * MB);   //  8 MB  [B,H,S,DH]
  u16*   aob  = (u16*)(ws + 48 * MB);   //  8 MB  attn out [B,S,D]
  u16*   vtb  = (u16*)(ws + 56 * MB);   //  8 MB  V^T [B,H,DH,S]
  float* x2   = (float*)(ws + 64 * MB); // 16 MB  fp32 residual
  u16*   h2   = hb;                     // LN2 out reuses hb
  u16*   ff1  = qbuf;                   // 32 MB spans 32..64 (all dead by FF1)

  const dim3 blk(256);
  tconv4<<<dim3(32, 32, 4), blk, 0, stream>>>(Wq, Wk, Wv, Wo, Wqt, Wkt, Wvt, Wot);
  tconv<<<dim3(128, 32), blk, 0, stream>>>(W1, W1t, 1024, 4096);
  tconv<<<dim3(32, 128), blk, 0, stream>>>(W2, W2t, 4096, 1024);

  ln_fwd<<<4096, blk, 0, stream>>>(x, ln1g, ln1b, hb);

  // fused QKV: Bt = [Wq^T;Wk^T;Wv^T] rows 0..3071; V written transposed
  gemm_bt<EPI_QKV, 128, 32><<<dim3(24, 32), blk, 0, stream>>>(
      hb, Wqt, bq, bk, bv, nullptr, nullptr, qbuf, kbuf, vtb, 3072, 1024);

  attn_fwd<<<dim3(16, 32), dim3(512), 0, stream>>>(qbuf, kbuf, vtb, aob);

  gemm_bt<EPI_RES, 64, 64><<<dim3(8, 64), blk, 0, stream>>>(
      aob, Wot, bo, nullptr, nullptr, x, x2, nullptr, nullptr, nullptr, 1024, 1024);

  ln_fwd<<<4096, blk, 0, stream>>>(x2, ln2g, ln2b, h2);

  gemm_bt<EPI_GELU, 128, 32><<<dim3(32, 32), blk, 0, stream>>>(
      h2, W1t, b1, nullptr, nullptr, nullptr, nullptr, ff1, nullptr, nullptr, 4096, 1024);

  gemm_bt<EPI_RES, 64, 64><<<dim3(8, 64), blk, 0, stream>>>(
      ff1, W2t, b2, nullptr, nullptr, x2, (float*)d_out, nullptr, nullptr, nullptr, 1024, 4096);
}